// Round 1
// baseline (131.802 us; speedup 1.0000x reference)
//
#include <hip/hip_runtime.h>
#include <cmath>

#define Bn 32
#define Hn 512
#define Wn 512
#define PADn 4
#define TW 32
#define TH 32
#define RW (TW + 8)   // 40
#define RH (TH + 8)   // 40

struct GaussW { float g[9]; };

__global__ __launch_bounds__(256, 2) void fuse_loss_kernel(
    const float* __restrict__ vis, const float* __restrict__ ir,
    const float* __restrict__ fus, const float* __restrict__ mask,
    float* __restrict__ out, GaussW gw)
{
    // x = ir, y = vis, z = fuse (w unused, pads to 16B for ds_read_b128)
    __shared__ float4 s_in[RH][RW];
    // hb_ir, hb_vi, hg_ir, hg_vi
    __shared__ float4 s_h1[RH][TW];
    // hg_ir2, hg_vi2
    __shared__ float2 s_h2[RH][TW];
    __shared__ float  s_part[4];

    const int t  = threadIdx.x;
    const int x0 = blockIdx.x * TW;
    const int y0 = blockIdx.y * TH;
    const size_t base = (size_t)blockIdx.z * (size_t)(Hn * Wn);

    // ---- Phase A: stage halo region (zero padding outside image) ----
    for (int idx = t; idx < RH * RW; idx += 256) {
        int ry = idx / RW, rx = idx - ry * RW;
        int gy = y0 + ry - PADn, gx = x0 + rx - PADn;
        float4 v = make_float4(0.f, 0.f, 0.f, 0.f);
        if ((unsigned)gy < (unsigned)Hn && (unsigned)gx < (unsigned)Wn) {
            size_t o = base + (size_t)gy * Wn + gx;
            v.x = ir[o]; v.y = vis[o]; v.z = fus[o];
        }
        s_in[ry][rx] = v;
    }
    __syncthreads();

    // ---- Phase B: horizontal 9-tap pass over 40 rows x 32 cols ----
    for (int idx = t; idx < RH * TW; idx += 256) {
        int ry = idx >> 5, cx = idx & 31;
        float hb_ir = 0.f, hb_vi = 0.f;
        float hg_ir = 0.f, hg_vi = 0.f, hg_ir2 = 0.f, hg_vi2 = 0.f;
        #pragma unroll
        for (int dx = 0; dx < 9; ++dx) {
            float4 v = s_in[ry][cx + dx];
            float di = v.x - v.z;
            float dv = v.y - v.z;
            hb_ir = fmaf(di, di, hb_ir);
            hb_vi = fmaf(dv, dv, hb_vi);
            float g = gw.g[dx];
            hg_ir  = fmaf(g, v.x, hg_ir);
            hg_vi  = fmaf(g, v.y, hg_vi);
            hg_ir2 = fmaf(g, v.x * v.x, hg_ir2);
            hg_vi2 = fmaf(g, v.y * v.y, hg_vi2);
        }
        s_h1[ry][cx] = make_float4(hb_ir, hb_vi, hg_ir, hg_vi);
        s_h2[ry][cx] = make_float2(hg_ir2, hg_vi2);
    }
    __syncthreads();

    // ---- Phase C: vertical 9-tap pass + selection + partial mean ----
    float acc = 0.f;
    for (int idx = t; idx < TH * TW; idx += 256) {
        int ty = idx >> 5, tx = idx & 31;
        float b_ir = 0.f, b_vi = 0.f;
        float mu_ir = 0.f, mu_vi = 0.f, m2_ir = 0.f, m2_vi = 0.f;
        #pragma unroll
        for (int dy = 0; dy < 9; ++dy) {
            float4 h1 = s_h1[ty + dy][tx];
            float2 h2 = s_h2[ty + dy][tx];
            b_ir += h1.x;
            b_vi += h1.y;
            float g = gw.g[dy];
            mu_ir = fmaf(g, h1.z, mu_ir);
            mu_vi = fmaf(g, h1.w, mu_vi);
            m2_ir = fmaf(g, h2.x, m2_ir);
            m2_vi = fmaf(g, h2.y, m2_vi);
        }
        float mse_ir = b_ir * (1.f / 81.f);
        float mse_vi = b_vi * (1.f / 81.f);
        float var_ir = m2_ir - mu_ir * mu_ir;
        float var_vi = m2_vi - mu_vi * mu_vi;
        float m1 = (var_ir - var_vi > 0.f) ? 1.f : 0.f;
        float mk = mask[base + (size_t)(y0 + ty) * Wn + (x0 + tx)];
        float mir = (m1 + mk > 0.f) ? 1.f : 0.f;
        acc += mir * mse_ir + (1.f - mir) * mse_vi;
    }

    // ---- block reduction, one atomicAdd per block ----
    #pragma unroll
    for (int off = 32; off > 0; off >>= 1)
        acc += __shfl_down(acc, off, 64);
    int wave = t >> 6, lane = t & 63;
    if (lane == 0) s_part[wave] = acc;
    __syncthreads();
    if (t == 0) {
        float s = s_part[0] + s_part[1] + s_part[2] + s_part[3];
        atomicAdd(out, s * (1.f / ((float)Bn * (float)Hn * (float)Wn)));
    }
}

extern "C" void kernel_launch(void* const* d_in, const int* in_sizes, int n_in,
                              void* d_out, int out_size, void* d_ws, size_t ws_size,
                              hipStream_t stream) {
    const float* vis  = (const float*)d_in[0];
    const float* ir   = (const float*)d_in[1];
    const float* fus  = (const float*)d_in[2];
    const float* mask = (const float*)d_in[3];
    float* out = (float*)d_out;

    // Gaussian weights in double, normalized, cast to fp32 (matches numpy)
    GaussW gw;
    double g[9], s = 0.0;
    for (int i = 0; i < 9; ++i) {
        int x = i - 4;
        g[i] = exp(-(double)(x * x) / 4.5);
        s += g[i];
    }
    for (int i = 0; i < 9; ++i) gw.g[i] = (float)(g[i] / s);

    hipMemsetAsync(d_out, 0, sizeof(float), stream);
    dim3 grid(Wn / TW, Hn / TH, Bn);
    fuse_loss_kernel<<<grid, 256, 0, stream>>>(vis, ir, fus, mask, out, gw);
}